// Round 8
// baseline (16.940 us; speedup 1.0000x reference)
//
#include <hip/hip_runtime.h>

#define NU 8192
#define NI 8192
#define DM 32
#define KC 32
#define HEADS 4
#define HK 8
#define BIASV 0.1f

#define UBLK 128   // user blocks in K1

// ---- K1: 128 blocks x 256 threads; 4 threads/row, 8 channels each.
// Raw keys live in registers only; emit per-block column sum(exp) and max.
__global__ __launch_bounds__(256) void k_part(
    const float* __restrict__ U,
    const float* __restrict__ Wk, const float* __restrict__ bk,
    float* __restrict__ part_s, float* __restrict__ part_m)
{
    __shared__ __align__(16) float Ws[DM * KC];
    __shared__ float bs[KC];
    __shared__ float wps[4][KC], wpm[4][KC];

    const int blk = blockIdx.x, t = threadIdx.x;
    const int row = (blk * 256 + t) >> 2;   // 64 rows/block
    const int qr  = t & 3;                  // channel quarter

    // issue per-row loads first; latency hides under weight staging + barrier
    const float4* ev = (const float4*)(U + row * DM);
    float4 v0 = ev[0], v1 = ev[1], v2 = ev[2], v3 = ev[3],
           v4 = ev[4], v5 = ev[5], v6 = ev[6], v7 = ev[7];

    // whole Wk = 1024 floats = 256 float4 -> exactly one per thread
    ((float4*)Ws)[t] = ((const float4*)Wk)[t];
    if (t < KC) bs[t] = bk[t];
    __syncthreads();

    const float e[DM] = {v0.x,v0.y,v0.z,v0.w, v1.x,v1.y,v1.z,v1.w,
                         v2.x,v2.y,v2.z,v2.w, v3.x,v3.y,v3.z,v3.w,
                         v4.x,v4.y,v4.z,v4.w, v5.x,v5.y,v5.z,v5.w,
                         v6.x,v6.y,v6.z,v6.w, v7.x,v7.y,v7.z,v7.w};
    float sx[HK], mx[HK];
    #pragma unroll
    for (int j = 0; j < HK; ++j) {
        float s = bs[qr * HK + j];
        #pragma unroll
        for (int d = 0; d < DM; ++d) s += e[d] * Ws[d * KC + qr * HK + j];
        mx[j] = s; sx[j] = __expf(s);
    }
    #pragma unroll
    for (int m = 4; m < 64; m <<= 1) {
        #pragma unroll
        for (int j = 0; j < HK; ++j) {
            sx[j] += __shfl_xor(sx[j], m, 64);
            mx[j]  = fmaxf(mx[j], __shfl_xor(mx[j], m, 64));
        }
    }
    const int lane = t & 63, wv = t >> 6;
    if (lane < 4) {
        #pragma unroll
        for (int j = 0; j < HK; ++j) {
            wps[wv][lane * HK + j] = sx[j];
            wpm[wv][lane * HK + j] = mx[j];
        }
    }
    __syncthreads();
    if (t < KC) {
        part_s[blk * KC + t] = wps[0][t] + wps[1][t] + wps[2][t] + wps[3][t];
        part_m[blk * KC + t] = fmaxf(fmaxf(wpm[0][t], wpm[1][t]),
                                     fmaxf(wpm[2][t], wpm[3][t]));
    }
}

// ---- K2: merge partials -> global activity flag (identical, deterministic in
// every block). Inactive: out = I + br. Active: fully self-contained general
// path (recompute q and normalized keys from inputs; accumulate; reproject).
// bound: sum_c k*q <= max_c k_norm (q>=0, sum_c q=1); exists active pair
//        <=> exists c: exp(colmax_c) > BIAS * S_c.
__global__ __launch_bounds__(256) void k_out(
    const float* __restrict__ U, const float* __restrict__ I,
    const float* __restrict__ Wk, const float* __restrict__ bk,
    const float* __restrict__ Wq, const float* __restrict__ bq,
    const float* __restrict__ Wr, const float* __restrict__ br,
    const float* __restrict__ part_s, const float* __restrict__ part_m,
    float* __restrict__ out)
{
    __shared__ __align__(16) float red_s[32][36];  // [srow][channel], pad->conflict-free
    __shared__ __align__(16) float red_m[32][36];
    __shared__ float sinv[KC];

    const int t = threadIdx.x;
    const int g = blockIdx.x * 256 + t;

    // issue output-path loads first; independent of partials
    const float4 iv  = ((const float4*)I)[g];
    const float4 brv = ((const float4*)br)[t & 7];

    // stage 1: 1024 float4s per array; 8 fully-independent loads per thread
    const float4* ps4 = (const float4*)part_s;
    const float4* pm4 = (const float4*)part_m;
    float4 s0 = ps4[t], s1 = ps4[t + 256], s2 = ps4[t + 512], s3 = ps4[t + 768];
    float4 m0 = pm4[t], m1 = pm4[t + 256], m2 = pm4[t + 512], m3 = pm4[t + 768];
    float4 vs = make_float4(s0.x + s1.x + s2.x + s3.x,
                            s0.y + s1.y + s2.y + s3.y,
                            s0.z + s1.z + s2.z + s3.z,
                            s0.w + s1.w + s2.w + s3.w);
    float4 vm = make_float4(fmaxf(fmaxf(m0.x, m1.x), fmaxf(m2.x, m3.x)),
                            fmaxf(fmaxf(m0.y, m1.y), fmaxf(m2.y, m3.y)),
                            fmaxf(fmaxf(m0.z, m1.z), fmaxf(m2.z, m3.z)),
                            fmaxf(fmaxf(m0.w, m1.w), fmaxf(m2.w, m3.w)));
    const int srow = t >> 3, quad = t & 7;
    *(float4*)&red_s[srow][quad * 4] = vs;   // 144B row stride, 16B-aligned
    *(float4*)&red_m[srow][quad * 4] = vm;
    __syncthreads();

    // stage 2: each thread reduces its channel over the 32 srows (LDS, conflict-free)
    const int c = t & 31;
    float ss = 0.f, mm = -1e30f;
    #pragma unroll
    for (int s = 0; s < 32; ++s) { ss += red_s[s][c]; mm = fmaxf(mm, red_m[s][c]); }
    const int anyactive = __syncthreads_or(__expf(mm) > BIASV * ss);

    if (!anyactive) {   // fast path: one float4 per thread, data already in flight
        ((float4*)out)[g] = make_float4(iv.x + brv.x, iv.y + brv.y,
                                        iv.z + brv.z, iv.w + brv.w);
        return;
    }

    // ---- general path (correctness; not taken on bench data) ----
    if (t < KC) sinv[t] = 1.f / ss;   // t<32 -> c==t

    __shared__ float Wk_s[DM * KC], Wq_s[DM * KC];
    __shared__ float bk_s[KC], bq_s[KC];
    __shared__ float q_s[32][KC];
    __shared__ float U_s[64][DM];
    __shared__ float k_s[64][KC];
    __shared__ float agg[32][HEADS * DM];

    for (int i = t; i < DM * KC; i += 256) { Wk_s[i] = Wk[i]; Wq_s[i] = Wq[i]; }
    if (t < KC) { bk_s[t] = bk[t]; bq_s[t] = bq[t]; }
    __syncthreads();

    const int itbase = blockIdx.x * 32;
    if (t < 128) {   // q for this block's 32 items: 1 thread per (item, head)
        const int il = t >> 2, h = t & 3;
        const float* Ir = I + (itbase + il) * DM;
        float o[HK];
        #pragma unroll
        for (int j = 0; j < HK; ++j) {
            float s2 = bq_s[h * HK + j];
            #pragma unroll
            for (int d = 0; d < DM; ++d) s2 += Ir[d] * Wq_s[d * KC + h * HK + j];
            o[j] = s2;
        }
        float m2 = o[0];
        #pragma unroll
        for (int j = 1; j < HK; ++j) m2 = fmaxf(m2, o[j]);
        float s3 = 0.f;
        #pragma unroll
        for (int j = 0; j < HK; ++j) { o[j] = __expf(o[j] - m2); s3 += o[j]; }
        const float inv = 1.f / s3;
        #pragma unroll
        for (int j = 0; j < HK; ++j) q_s[il][h * HK + j] = o[j] * inv;
    }

    const int il  = t >> 3;   // item-local 0..31
    const int sub = t & 7;    // 4 d-channels
    float acc[HEADS][4] = {{0.f}};

    for (int cu = 0; cu < NU / 64; ++cu) {
        __syncthreads();
        for (int i = t; i < 64 * DM; i += 256) U_s[i >> 5][i & 31] = U[cu * 64 * DM + i];
        __syncthreads();
        {   // keys chunk: 1 thread per (user-local, quarter)
            const int lu = t >> 2, qh = t & 3;
            float o[HK];
            #pragma unroll
            for (int j = 0; j < HK; ++j) {
                float s2 = bk_s[qh * HK + j];
                #pragma unroll
                for (int d = 0; d < DM; ++d) s2 += U_s[lu][d] * Wk_s[d * KC + qh * HK + j];
                o[j] = s2;
            }
            #pragma unroll
            for (int j = 0; j < HK; ++j)
                k_s[lu][qh * HK + j] = __expf(o[j]) * sinv[qh * HK + j];
        }
        __syncthreads();
        for (int lu = 0; lu < 64; ++lu) {
            #pragma unroll
            for (int h = 0; h < HEADS; ++h) {
                float s2 = 0.f;
                #pragma unroll
                for (int cc = 0; cc < HK; ++cc) s2 += k_s[lu][h * HK + cc] * q_s[il][h * HK + cc];
                s2 -= BIASV;
                if (s2 > 0.f) {
                    #pragma unroll
                    for (int jj = 0; jj < 4; ++jj) acc[h][jj] += s2 * U_s[lu][sub * 4 + jj];
                }
            }
        }
    }
    #pragma unroll
    for (int h = 0; h < HEADS; ++h)
        #pragma unroll
        for (int jj = 0; jj < 4; ++jj)
            agg[il][h * DM + sub * 4 + jj] = acc[h][jj];
    __syncthreads();

    float r[4];
    #pragma unroll
    for (int cc = 0; cc < 4; ++cc) r[cc] = br[sub * 4 + cc];
    for (int j = 0; j < HEADS * DM; ++j) {
        const float a = agg[il][j];
        #pragma unroll
        for (int cc = 0; cc < 4; ++cc) r[cc] += a * Wr[j * KC + sub * 4 + cc];
    }
    #pragma unroll
    for (int cc = 0; cc < 4; ++cc) {
        const int idx = (itbase + il) * KC + sub * 4 + cc;
        out[idx] = I[idx] + r[cc];
    }
}

extern "C" void kernel_launch(void* const* d_in, const int* in_sizes, int n_in,
                              void* d_out, int out_size, void* d_ws, size_t ws_size,
                              hipStream_t stream) {
    const float* U  = (const float*)d_in[0];
    const float* I  = (const float*)d_in[1];
    const float* Wk = (const float*)d_in[2];
    const float* bk = (const float*)d_in[3];
    const float* Wq = (const float*)d_in[4];
    const float* bq = (const float*)d_in[5];
    const float* Wr = (const float*)d_in[6];
    const float* br = (const float*)d_in[7];
    float* out = (float*)d_out;

    float* ws_ps = (float*)d_ws;          // UBLK*KC
    float* ws_pm = ws_ps + UBLK * KC;     // UBLK*KC

    k_part<<<UBLK, 256, 0, stream>>>(U, Wk, bk, ws_ps, ws_pm);
    k_out<<<256, 256, 0, stream>>>(U, I, Wk, bk, Wq, bq, Wr, br, ws_ps, ws_pm, out);
}

// Round 9
// 13.348 us; speedup vs baseline: 1.2691x; 1.2691x over previous
//
#include <hip/hip_runtime.h>

#define NU 8192
#define NI 8192
#define DM 32
#define KC 32
#define HEADS 4
#define HK 8
#define BIASV 0.1f

#define UBLK 128   // user blocks in K1

// ---- K1: 128 blocks x 256 threads; 4 threads/row, 8 channels each.
// Raw keys live in registers only; emit per-block column sum(exp) and max.
__global__ __launch_bounds__(256) void k_part(
    const float* __restrict__ U,
    const float* __restrict__ Wk, const float* __restrict__ bk,
    float* __restrict__ part_s, float* __restrict__ part_m)
{
    __shared__ float Ws[DM * KC];
    __shared__ float bs[KC];
    __shared__ float wps[4][KC], wpm[4][KC];

    const int blk = blockIdx.x, t = threadIdx.x;
    const int row = (blk * 256 + t) >> 2;   // 64 rows/block
    const int qr  = t & 3;                  // channel quarter

    // issue per-row loads first; latency hides under weight staging + barrier
    const float4* ev = (const float4*)(U + row * DM);
    float4 v0 = ev[0], v1 = ev[1], v2 = ev[2], v3 = ev[3],
           v4 = ev[4], v5 = ev[5], v6 = ev[6], v7 = ev[7];

    for (int i = t; i < DM * KC; i += 256) Ws[i] = Wk[i];
    if (t < KC) bs[t] = bk[t];
    __syncthreads();

    const float e[DM] = {v0.x,v0.y,v0.z,v0.w, v1.x,v1.y,v1.z,v1.w,
                         v2.x,v2.y,v2.z,v2.w, v3.x,v3.y,v3.z,v3.w,
                         v4.x,v4.y,v4.z,v4.w, v5.x,v5.y,v5.z,v5.w,
                         v6.x,v6.y,v6.z,v6.w, v7.x,v7.y,v7.z,v7.w};
    float sx[HK], mx[HK];
    #pragma unroll
    for (int j = 0; j < HK; ++j) {
        float s = bs[qr * HK + j];
        #pragma unroll
        for (int d = 0; d < DM; ++d) s += e[d] * Ws[d * KC + qr * HK + j];
        mx[j] = s; sx[j] = __expf(s);
    }
    #pragma unroll
    for (int m = 4; m < 64; m <<= 1) {
        #pragma unroll
        for (int j = 0; j < HK; ++j) {
            sx[j] += __shfl_xor(sx[j], m, 64);
            mx[j]  = fmaxf(mx[j], __shfl_xor(mx[j], m, 64));
        }
    }
    const int lane = t & 63, wv = t >> 6;
    if (lane < 4) {
        #pragma unroll
        for (int j = 0; j < HK; ++j) {
            wps[wv][lane * HK + j] = sx[j];
            wpm[wv][lane * HK + j] = mx[j];
        }
    }
    __syncthreads();
    if (t < KC) {
        part_s[blk * KC + t] = wps[0][t] + wps[1][t] + wps[2][t] + wps[3][t];
        part_m[blk * KC + t] = fmaxf(fmaxf(wpm[0][t], wpm[1][t]),
                                     fmaxf(wpm[2][t], wpm[3][t]));
    }
}

// ---- K2: merge partials -> global activity flag (identical, deterministic in
// every block). Inactive: out = I + br. Active: fully self-contained general
// path (recompute q and normalized keys from inputs; accumulate; reproject).
// bound: sum_c k*q <= max_c k_norm (q>=0, sum_c q=1); exists active pair
//        <=> exists c: exp(colmax_c) > BIAS * S_c.
__global__ __launch_bounds__(256) void k_out(
    const float* __restrict__ U, const float* __restrict__ I,
    const float* __restrict__ Wk, const float* __restrict__ bk,
    const float* __restrict__ Wq, const float* __restrict__ bq,
    const float* __restrict__ Wr, const float* __restrict__ br,
    const float* __restrict__ part_s, const float* __restrict__ part_m,
    float* __restrict__ out)
{
    __shared__ float red_s[8][KC], red_m[8][KC];
    __shared__ float sinv[KC];

    const int t = threadIdx.x;
    const int g = blockIdx.x * 256 + t;

    // issue output-path loads first; independent of partials
    const float4 iv  = ((const float4*)I)[g];
    const float4 brv = ((const float4*)br)[t & 7];

    const int c = t & 31, ch = t >> 5;
    {
        float s = 0.f, m = -1e30f;
        #pragma unroll 4
        for (int b = ch; b < UBLK; b += 8) {
            s += part_s[b * KC + c];
            m = fmaxf(m, part_m[b * KC + c]);
        }
        red_s[ch][c] = s; red_m[ch][c] = m;
    }
    __syncthreads();
    float ss = 0.f, mm = -1e30f;
    #pragma unroll
    for (int i = 0; i < 8; ++i) { ss += red_s[i][c]; mm = fmaxf(mm, red_m[i][c]); }
    const int anyactive = __syncthreads_or(__expf(mm) > BIASV * ss);

    if (!anyactive) {   // fast path: one float4 per thread, data already in flight
        ((float4*)out)[g] = make_float4(iv.x + brv.x, iv.y + brv.y,
                                        iv.z + brv.z, iv.w + brv.w);
        return;
    }

    // ---- general path (correctness; not taken on bench data) ----
    if (ch == 0) sinv[c] = 1.f / ss;

    __shared__ float Wk_s[DM * KC], Wq_s[DM * KC];
    __shared__ float bk_s[KC], bq_s[KC];
    __shared__ float q_s[32][KC];
    __shared__ float U_s[64][DM];
    __shared__ float k_s[64][KC];
    __shared__ float agg[32][HEADS * DM];

    for (int i = t; i < DM * KC; i += 256) { Wk_s[i] = Wk[i]; Wq_s[i] = Wq[i]; }
    if (t < KC) { bk_s[t] = bk[t]; bq_s[t] = bq[t]; }
    __syncthreads();

    const int itbase = blockIdx.x * 32;
    if (t < 128) {   // q for this block's 32 items: 1 thread per (item, head)
        const int il = t >> 2, h = t & 3;
        const float* Ir = I + (itbase + il) * DM;
        float o[HK];
        #pragma unroll
        for (int j = 0; j < HK; ++j) {
            float s2 = bq_s[h * HK + j];
            #pragma unroll
            for (int d = 0; d < DM; ++d) s2 += Ir[d] * Wq_s[d * KC + h * HK + j];
            o[j] = s2;
        }
        float m2 = o[0];
        #pragma unroll
        for (int j = 1; j < HK; ++j) m2 = fmaxf(m2, o[j]);
        float s3 = 0.f;
        #pragma unroll
        for (int j = 0; j < HK; ++j) { o[j] = __expf(o[j] - m2); s3 += o[j]; }
        const float inv = 1.f / s3;
        #pragma unroll
        for (int j = 0; j < HK; ++j) q_s[il][h * HK + j] = o[j] * inv;
    }

    const int il  = t >> 3;   // item-local 0..31
    const int sub = t & 7;    // 4 d-channels
    float acc[HEADS][4] = {{0.f}};

    for (int cu = 0; cu < NU / 64; ++cu) {
        __syncthreads();
        for (int i = t; i < 64 * DM; i += 256) U_s[i >> 5][i & 31] = U[cu * 64 * DM + i];
        __syncthreads();
        {   // keys chunk: 1 thread per (user-local, quarter)
            const int lu = t >> 2, qh = t & 3;
            float o[HK];
            #pragma unroll
            for (int j = 0; j < HK; ++j) {
                float s2 = bk_s[qh * HK + j];
                #pragma unroll
                for (int d = 0; d < DM; ++d) s2 += U_s[lu][d] * Wk_s[d * KC + qh * HK + j];
                o[j] = s2;
            }
            #pragma unroll
            for (int j = 0; j < HK; ++j)
                k_s[lu][qh * HK + j] = __expf(o[j]) * sinv[qh * HK + j];
        }
        __syncthreads();
        for (int lu = 0; lu < 64; ++lu) {
            #pragma unroll
            for (int h = 0; h < HEADS; ++h) {
                float s2 = 0.f;
                #pragma unroll
                for (int cc = 0; cc < HK; ++cc) s2 += k_s[lu][h * HK + cc] * q_s[il][h * HK + cc];
                s2 -= BIASV;
                if (s2 > 0.f) {
                    #pragma unroll
                    for (int jj = 0; jj < 4; ++jj) acc[h][jj] += s2 * U_s[lu][sub * 4 + jj];
                }
            }
        }
    }
    #pragma unroll
    for (int h = 0; h < HEADS; ++h)
        #pragma unroll
        for (int jj = 0; jj < 4; ++jj)
            agg[il][h * DM + sub * 4 + jj] = acc[h][jj];
    __syncthreads();

    float r[4];
    #pragma unroll
    for (int cc = 0; cc < 4; ++cc) r[cc] = br[sub * 4 + cc];
    for (int j = 0; j < HEADS * DM; ++j) {
        const float a = agg[il][j];
        #pragma unroll
        for (int cc = 0; cc < 4; ++cc) r[cc] += a * Wr[j * KC + sub * 4 + cc];
    }
    #pragma unroll
    for (int cc = 0; cc < 4; ++cc) {
        const int idx = (itbase + il) * KC + sub * 4 + cc;
        out[idx] = I[idx] + r[cc];
    }
}

extern "C" void kernel_launch(void* const* d_in, const int* in_sizes, int n_in,
                              void* d_out, int out_size, void* d_ws, size_t ws_size,
                              hipStream_t stream) {
    const float* U  = (const float*)d_in[0];
    const float* I  = (const float*)d_in[1];
    const float* Wk = (const float*)d_in[2];
    const float* bk = (const float*)d_in[3];
    const float* Wq = (const float*)d_in[4];
    const float* bq = (const float*)d_in[5];
    const float* Wr = (const float*)d_in[6];
    const float* br = (const float*)d_in[7];
    float* out = (float*)d_out;

    float* ws_ps = (float*)d_ws;          // UBLK*KC
    float* ws_pm = ws_ps + UBLK * KC;     // UBLK*KC

    k_part<<<UBLK, 256, 0, stream>>>(U, Wk, bk, ws_ps, ws_pm);
    k_out<<<256, 256, 0, stream>>>(U, I, Wk, bk, Wq, bq, Wr, br, ws_ps, ws_pm, out);
}